// Round 5
// baseline (590.157 us; speedup 1.0000x reference)
//
#include <hip/hip_runtime.h>

#define LSZ 64
#define TILE 16

typedef _Float16 f16x8 __attribute__((ext_vector_type(8)));
typedef float    f32x4 __attribute__((ext_vector_type(4)));

// LDS plan (33,888 B -> 4 blocks/CU):  [R20 address map; R22 = R20 + exact
// integer addressing trims, K16 tail REVERTED]
//  s_h1: 20 grid-rows x 1,696 B row pitch = 33,824 B
//        position (ry,rx) at f16 index ry*848 + rx*40 ([hi x16][lo x16][pad 8])
//        R20: +96 B/row pitch makes the phase-2 coset walk uniform across
//        18->20 row wraps (in-row step 20 ≡ wrap step 84 mod 32) -> conv2
//        reads conflict-minimal (verified: conflicts 2.77e7 -> 2.08e7).
//        ALIASED by s_h2 (f32 position-major [pos][20], 25,920 B) after conv2;
//        conv2 D staged in registers (Cs[6][8]) across the barrier.
//  s_bits: 16 u32 = 64 B (ballot-packed sign bits, R18; absmax=0 verified)
//
// d_ws (f16): [0) conv2 K32 frags 4x5120  [20480) h1 tables 4x1536 (53,248 B)
//
// MFMA RULE (R21 FAILED, R7 sharpened): NEVER change the MFMA shape or
//   K-decomposition of the verified conv2 reduction. A K32->K16 tail (pad
//   terms were exact +0) still flipped output signs (absmax 2.0): the
//   16-wide instruction's internal reduction tree is NOT the first-half
//   subtree of the 32-wide one, and logit sign margins are ulp-thin.
//   Bit-identity must hold at the INSTRUCTION level, not just term-set level.
// PERF MODEL (R19/R20 measured): nothing saturated — VALU+MFMA ~60%, MFMA
//   pipe 26%, LDS ~50-70%, HBM 5%; occupancy 4 vs 5 blocks/CU neutral;
//   conflict removal only ~20% effective. => distributed-overhead regime:
//   wins come from instruction-count cuts, not occupancy/conflict tuning.
// OCCUPANCY RULE (R11/R15/R19): __launch_bounds__ MUST stay (256,4) — the
//   2nd arg is a register-allocator FLOOR; (256,5) forced VGPR 60->48 and
//   spilled ~12 dwords/thread (R18: WRITE_SIZE 16MB->221MB, dur 148->232 us).
// COMPILER RULE (R12/R13): don't fully unroll multi-load bodies (spill).
// LAYOUT RULE (R13): h1/h2 strides must keep 16 B alignment for b128.
// NUMERICS RULE (R7): everything feeding a USED logit stays bit-identical.
// R17: phase-4 lane map row-interleaved -> conv3 b128 reads at the
// 8-touch/bank minimum.
// R22 exact-integer trims (provably address-identical): phase-2 oy/ox by
//   incremental walk (m_abs += 64 => ox += 10, oy += 3, single wrap at 18);
//   phase-0 iter-2 indices by increment (+256 = 11 rows + 14 cols).

__device__ __forceinline__ float fast_tanh(float x) {
    float ax = __builtin_fabsf(x);
    float t  = __builtin_amdgcn_exp2f(ax * -2.885390081777927f);
    float r  = (1.0f - t) * __builtin_amdgcn_rcpf(1.0f + t);
    return __builtin_copysignf(r, x);
}

__device__ __forceinline__ void split_f16(float x, _Float16& hi, _Float16& lo) {
    float h0 = (float)(_Float16)x;
    if (__builtin_fabsf(h0) < 6.104e-5f) h0 = 0.0f;
    hi = (_Float16)h0;
    lo = (_Float16)((x - h0) * 2048.0f);
}

__global__ void prep(const float* __restrict__ W0, const float* __restrict__ B0,
                     const float* __restrict__ W1, _Float16* __restrict__ ws) {
    const int layer = blockIdx.x, tid = threadIdx.x;
    const float* w1g = W1 + layer * 2304;
    _Float16* o2 = ws + layer * 5120;
    for (int e = tid; e < 320; e += 256) {
        int c = e >> 6, lane = e & 63;
        int q = lane >> 4, co = lane & 15;
        #pragma unroll
        for (int j = 0; j < 8; ++j) {
            int k = c * 32 + q * 8 + j;
            float w = (k < 144) ? w1g[k * 16 + co] : 0.0f;
            _Float16 whi, wlo;
            split_f16(w, whi, wlo);
            o2[((c * 2 + 0) * 64 + lane) * 8 + j] = whi;
            o2[((c * 2 + 1) * 64 + lane) * 8 + j] = wlo;
        }
    }
    const float* w0g = W0 + layer * 144;
    const float* b0g = B0 + layer * 16;
    _Float16* ot = ws + 20480 + layer * 1536;
    for (int e = tid; e < 48; e += 256) {
        int sel = (e >= 32);
        int bits = sel ? (e - 32) : e;
        const int wtE[5] = {0, 2, 4, 6, 8};   // taps (0,0)(0,2)(1,1)(2,0)(2,2)
        const int wtO[4] = {1, 3, 5, 7};      // taps (0,1)(1,0)(1,2)(2,1)
        for (int ch = 0; ch < 16; ++ch) {
            float u = b0g[ch];
            if (!sel) {
                #pragma unroll
                for (int t = 0; t < 5; ++t) {
                    float s = ((bits >> t) & 1) ? 1.0f : -1.0f;
                    u = fmaf(s, w0g[wtE[t] * 16 + ch], u);
                }
            } else {
                #pragma unroll
                for (int t = 0; t < 4; ++t) {
                    float s = ((bits >> t) & 1) ? 1.0f : -1.0f;
                    u = fmaf(s, w0g[wtO[t] * 16 + ch], u);
                }
            }
            _Float16 hi, lo;
            split_f16(fast_tanh(u), hi, lo);
            ot[e * 32 + ch]      = hi;
            ot[e * 32 + 16 + ch] = lo;
        }
    }
}

__global__ __launch_bounds__(256, 4)
void discrete_flow_layer(const float* x_in,
                         float* x_out,
                         const _Float16* __restrict__ wfr,
                         const _Float16* __restrict__ tbl,
                         const float* __restrict__ b1g,
                         const float* __restrict__ w2g,
                         const float* __restrict__ b2g,
                         int parityA, int writeA)
{
    __shared__ __align__(16) _Float16 s_h1[16912];      // 20 rows x 848 f16
    __shared__ unsigned s_bits[16];                     // 22x22 sign bits
    float* s_h2 = (float*)s_h1;                          // [pos][20] after barrier

    const int tid  = threadIdx.x;
    const int lane = tid & 63;
    const int wv   = tid >> 6;
    const int tile = blockIdx.x;
    const int b    = blockIdx.y;
    const int r0 = (tile >> 2) * TILE;
    const int c0 = (tile & 3) * TILE;
    const float* xb = x_in + (size_t)b * (LSZ * LSZ);

    // ---- prefetch conv2 weight fragments + bias (global, L2-hot) ----
    f16x8 Bh[5], Bl[5];
    #pragma unroll
    for (int c = 0; c < 5; ++c) {
        Bh[c] = *(const f16x8*)&wfr[((c * 2 + 0) * 64 + lane) * 8];
        Bl[c] = *(const f16x8*)&wfr[((c * 2 + 1) * 64 + lane) * 8];
    }
    const float b1v = b1g[lane & 15];

    // ---- phase 0: ballot-pack masked sign bits of the 22x22 halo tile ----
    // bit = (A-parity) && (x > 0). R22: iter-2 indices by increment
    // (+256 = 11 rows + 14 cols), bit-exact vs the /22,%22 pair.
    {
        int r = tid / 22, c = tid - r * 22;
        #pragma unroll
        for (int it = 0; it < 2; ++it) {
            int idx = tid + it * 256;
            int gr = (r0 + r - 3) & 63;
            int gc = (c0 + c - 3) & 63;
            float v = xb[gr * 64 + gc];          // wrapped address, always valid
            bool bit = (idx < 484) && (((gr + gc) & 1) == parityA) && (v > 0.0f);
            unsigned long long m = __ballot(bit);
            if ((lane & 31) == 0)
                s_bits[it * 8 + wv * 2 + (lane >> 5)] = (unsigned)(m >> (lane & 32));
            r += 11; c += 14;
            if (c >= 22) { c -= 22; r += 1; }
        }
    }
    __syncthreads();

    // ---- phase 1: h1 by pattern-table lookup (index from bit array) ----
    for (int pp = tid; pp < 400; pp += 256) {
        int g  = (pp >= 200);
        int pi = pp - g * 200;
        int ry = pi / 10;
        int rx = 2 * (pi % 10) + ((ry ^ g) & 1);
        int base = ry * 22 + rx;
        int sel = g ^ parityA;
        int idx = 0;
        if (sel == 0) {                        // even-sum taps
            const int off[5] = {0, 2, 23, 44, 46};
            #pragma unroll
            for (int t = 0; t < 5; ++t) {
                int p = base + off[t];
                idx |= ((s_bits[p >> 5] >> (p & 31)) & 1) << t;
            }
        } else {                               // odd-sum taps
            const int off[4] = {1, 22, 24, 45};
            #pragma unroll
            for (int t = 0; t < 4; ++t) {
                int p = base + off[t];
                idx |= ((s_bits[p >> 5] >> (p & 31)) & 1) << t;
            }
        }
        const f16x8* row = (const f16x8*)&tbl[(sel ? 1024 : 0) + idx * 32];
        f16x8* hp = (f16x8*)&s_h1[ry * 848 + rx * 40];
        hp[0] = row[0]; hp[1] = row[1]; hp[2] = row[2]; hp[3] = row[3];
    }
    __syncthreads();

    // ---- phase 2: conv2 MFMA (M=324, N=16, K=144->160); D -> registers ----
    float Cs[6][8];
    {
        const int m0 = lane & 15, q = lane >> 4;
        const int qh = q >> 1, ql = q & 1;
        // T offsets for row pitch 848 f16 (grid step: col=+40, row=+848)
        const int T0 = 0, T1 = 40, T2 = 80, T3 = 848, T4 = 888,
                  T5 = 928, T6 = 1696, T7 = 1736, T8 = 1776, T9 = 1776;
        // div-free incremental position walk: m_abs += 64 per s (R22, exact)
        int m_lin = wv * 16 + m0;              // <= 63 at s=0
        int oyc = (m_lin >= 18) + (m_lin >= 36) + (m_lin >= 54);
        int oxc = m_lin - oyc * 18;
        #pragma unroll
        for (int s = 0; s < 6; ++s) {
            int mt = wv + s * 4;
            if (mt < 21) {
                int oy = oyc, ox = oxc;
                if (mt == 20 && m0 > 3) { oy = 17; ox = 17; }  // clamp -> 323
                int abase = oy * 848 + ox * 40 + ql * 8;
                f32x4 C0 = {0.f, 0.f, 0.f, 0.f};
                f32x4 C1 = {0.f, 0.f, 0.f, 0.f};
                int off;
                f16x8 A0, A1;
                #define CONV2_STEP(cc, TA, TB)                                        \
                    off = qh ? (TB) : (TA);                                           \
                    A0 = *(const f16x8*)&s_h1[abase + off];                           \
                    A1 = *(const f16x8*)&s_h1[abase + off + 16];                      \
                    C0 = __builtin_amdgcn_mfma_f32_16x16x32_f16(A0, Bh[cc], C0, 0, 0, 0); \
                    C1 = __builtin_amdgcn_mfma_f32_16x16x32_f16(A0, Bl[cc], C1, 0, 0, 0); \
                    C1 = __builtin_amdgcn_mfma_f32_16x16x32_f16(A1, Bh[cc], C1, 0, 0, 0);
                CONV2_STEP(0, T0, T1)
                CONV2_STEP(1, T2, T3)
                CONV2_STEP(2, T4, T5)
                CONV2_STEP(3, T6, T7)
                CONV2_STEP(4, T8, T9)
                #undef CONV2_STEP
                #pragma unroll
                for (int r = 0; r < 4; ++r) { Cs[s][r] = C0[r]; Cs[s][4 + r] = C1[r]; }
            }
            oxc += 10; oyc += 3;
            if (oxc >= 18) { oxc -= 18; oyc += 1; }
        }
    }
    __syncthreads();   // ALL h1 reads complete -> safe to overwrite (h2 alias)

    // ---- phase 3: epilogue, bit-identical h2 values, position-major f32 ----
    {
        const int m0 = lane & 15, q = lane >> 4;
        #pragma unroll
        for (int s = 0; s < 6; ++s) {
            int mt = wv + s * 4;
            if (mt < 21) {
                #pragma unroll
                for (int r = 0; r < 4; ++r) {
                    int m_out = mt * 16 + q * 4 + r;
                    if (m_out < 324) {
                        float val = Cs[s][r] + Cs[s][4 + r] * (1.0f / 2048.0f) + b1v;
                        s_h2[m_out * 20 + m0] = fast_tanh(val);
                    }
                }
            }
        }
    }
    __syncthreads();

    // ---- phase 4: conv3 at B-SITES ONLY, row-interleaved lane map ----
    // Consecutive lanes alternate adjacent rows -> odd p-steps -> start banks
    // cover all 8 cosets -> conv3 b128 reads at the 8-touch/bank minimum.
    // Per-site fmaf chain: tap kh-major kw-ascending, ci 0..15 ascending —
    // exact R15 order -> bit-identical logits.
    if (tid < 128) {
        int pr = tid >> 4;                     // row pair 0..7
        int j4 = tid & 15;
        int ry = pr * 2 + (j4 & 1);
        int k  = j4 >> 1;                      // 0..7
        int rx = 2 * k + ((ry + parityA + 1) & 1);   // B-parity col
        float acc = b2g[0];
        #pragma unroll
        for (int tap = 0; tap < 9; ++tap) {
            int kh = tap / 3, kw = tap % 3;
            const float* hv = &s_h2[((ry + kh) * 18 + rx + kw) * 20];
            float4 v0 = *(const float4*)&hv[0];
            float4 v1 = *(const float4*)&hv[4];
            float4 v2 = *(const float4*)&hv[8];
            float4 v3 = *(const float4*)&hv[12];
            const float* w = &w2g[tap * 16];
            acc = fmaf(v0.x, w[0],  acc); acc = fmaf(v0.y, w[1],  acc);
            acc = fmaf(v0.z, w[2],  acc); acc = fmaf(v0.w, w[3],  acc);
            acc = fmaf(v1.x, w[4],  acc); acc = fmaf(v1.y, w[5],  acc);
            acc = fmaf(v1.z, w[6],  acc); acc = fmaf(v1.w, w[7],  acc);
            acc = fmaf(v2.x, w[8],  acc); acc = fmaf(v2.y, w[9],  acc);
            acc = fmaf(v2.z, w[10], acc); acc = fmaf(v2.w, w[11], acc);
            acc = fmaf(v3.x, w[12], acc); acc = fmaf(v3.y, w[13], acc);
            acc = fmaf(v3.z, w[14], acc); acc = fmaf(v3.w, w[15], acc);
        }
        int gr = r0 + ry, gc = c0 + rx;
        size_t site = (size_t)b * (LSZ * LSZ) + gr * 64 + gc;
        float xv = x_in[site];
        float m = (acc > 0.0f) ? 1.0f : ((acc < 0.0f) ? -1.0f : 0.0f);
        x_out[site] = xv * m;
    } else if (writeA) {
        // A-site pass-through (layer 0 only)
        int t2 = tid - 128;
        int ry = t2 >> 3;
        int rx = 2 * (t2 & 7) + ((ry + parityA) & 1);        // A-parity col
        int gr = r0 + ry, gc = c0 + rx;
        size_t site = (size_t)b * (LSZ * LSZ) + gr * 64 + gc;
        x_out[site] = x_in[site];
    }
}

extern "C" void kernel_launch(void* const* d_in, const int* in_sizes, int n_in,
                              void* d_out, int out_size, void* d_ws, size_t ws_size,
                              hipStream_t stream) {
    const float* z  = (const float*)d_in[0];
    const float* W0 = (const float*)d_in[1];
    const float* B0 = (const float*)d_in[2];
    const float* W1 = (const float*)d_in[3];
    const float* B1 = (const float*)d_in[4];
    const float* W2 = (const float*)d_in[5];
    const float* B2 = (const float*)d_in[6];
    float* out = (float*)d_out;
    _Float16* ws = (_Float16*)d_ws;   // 53,248 B used

    prep<<<dim3(4), 256, 0, stream>>>(W0, B0, W1, ws);

    dim3 grid(16, 1024);
    for (int layer = 0; layer < 4; ++layer) {
        const float* xin = (layer == 0) ? z : out;
        int writeA = (layer == 0) ? 1 : 0;
        int parityA = layer & 1;
        discrete_flow_layer<<<grid, 256, 0, stream>>>(
            xin, out,
            ws + layer * 5120,
            ws + 20480 + layer * 1536,
            B1 + layer * 16,
            W2 + layer * 144,
            B2 + layer * 1,
            parityA, writeA);
    }
}

// Round 6
// 589.325 us; speedup vs baseline: 1.0014x; 1.0014x over previous
//
#include <hip/hip_runtime.h>

#define LSZ 64
#define TILE 16

typedef _Float16 f16x8 __attribute__((ext_vector_type(8)));
typedef float    f32x4 __attribute__((ext_vector_type(4)));

// LDS plan (34,480 B -> 4 blocks/CU):  [R22 base; R23 phase-4 memory restructure]
//  s_h1: 20 grid-rows x 1,696 B row pitch = 33,824 B
//        position (ry,rx) at f16 index ry*848 + rx*40 ([hi x16][lo x16][pad 8])
//        R20: +96 B/row pitch -> conv2 coset walk uniform across row wraps
//        (conflicts 2.77e7 -> 2.08e7, verified).
//        ALIASED by s_h2 (f32 position-major [pos][20], 25,920 B) after conv2;
//        conv2 D staged in registers (Cs[6][8]) across the barrier.
//  s_bits: 16 u32 = 64 B (ballot-packed sign bits, R18; absmax=0 verified)
//  s_w2:  145 f32 = 580 B (R23: conv3 weights + bias staged once per block)
//
// R23 THEORY (from occupancy 40% < 50% cap): waves 2,3 retire at the p3
//   barrier (layer>=1) -> 16*f + 8*(1-f) = 12.8 -> phase 4 ~= 40% of block
//   lifetime on half the waves. Cause: per tap, 16 uniform w2g loads emit
//   SMEM s_load which SHARES lgkmcnt with ds_read on gfx9 -> every wait
//   entangles; no VGPR headroom to pipeline -> ~9 taps of exposed latency.
//   Fix: weights -> LDS broadcast reads (DS-only waits) + manual 1-deep
//   prefetch of next tap's h2 float4s + early x_in load. Chain order and
//   values untouched -> bit-identical.
// MFMA RULE (R21 FAILED, R7 sharpened): NEVER change the MFMA shape or
//   K-decomposition of the verified conv2 reduction (K32->K16 tail flipped
//   signs: 16-wide reduction tree != first-half of 32-wide; margins are
//   ulp-thin). Bit-identity must hold at the INSTRUCTION level.
// PERF MODEL (R19/R20/R22 measured): no pipe saturated (VALU ~58%, MFMA
//   ~25%, HBM 5%); occupancy 4 vs 5 blocks/CU neutral; conflict -25% ->
//   dur -1.5%; addressing trims null. Latency/imbalance regime, not
//   throughput-bound.
// OCCUPANCY RULE (R11/R15/R19): __launch_bounds__ MUST stay (256,4) — the
//   2nd arg is a register-allocator FLOOR; (256,5) forced VGPR 60->48 and
//   spilled ~12 dwords/thread (R18: WRITE_SIZE 16MB->221MB, dur 148->232 us).
// COMPILER RULE (R12/R13): don't fully unroll multi-load bodies (spill).
// LAYOUT RULE (R13): h1/h2 strides must keep 16 B alignment for b128.
// NUMERICS RULE (R7): everything feeding a USED logit stays bit-identical.
// R17: phase-4 lane map row-interleaved -> conv3 b128 reads at the
// 8-touch/bank minimum.

__device__ __forceinline__ float fast_tanh(float x) {
    float ax = __builtin_fabsf(x);
    float t  = __builtin_amdgcn_exp2f(ax * -2.885390081777927f);
    float r  = (1.0f - t) * __builtin_amdgcn_rcpf(1.0f + t);
    return __builtin_copysignf(r, x);
}

__device__ __forceinline__ void split_f16(float x, _Float16& hi, _Float16& lo) {
    float h0 = (float)(_Float16)x;
    if (__builtin_fabsf(h0) < 6.104e-5f) h0 = 0.0f;
    hi = (_Float16)h0;
    lo = (_Float16)((x - h0) * 2048.0f);
}

__global__ void prep(const float* __restrict__ W0, const float* __restrict__ B0,
                     const float* __restrict__ W1, _Float16* __restrict__ ws) {
    const int layer = blockIdx.x, tid = threadIdx.x;
    const float* w1g = W1 + layer * 2304;
    _Float16* o2 = ws + layer * 5120;
    for (int e = tid; e < 320; e += 256) {
        int c = e >> 6, lane = e & 63;
        int q = lane >> 4, co = lane & 15;
        #pragma unroll
        for (int j = 0; j < 8; ++j) {
            int k = c * 32 + q * 8 + j;
            float w = (k < 144) ? w1g[k * 16 + co] : 0.0f;
            _Float16 whi, wlo;
            split_f16(w, whi, wlo);
            o2[((c * 2 + 0) * 64 + lane) * 8 + j] = whi;
            o2[((c * 2 + 1) * 64 + lane) * 8 + j] = wlo;
        }
    }
    const float* w0g = W0 + layer * 144;
    const float* b0g = B0 + layer * 16;
    _Float16* ot = ws + 20480 + layer * 1536;
    for (int e = tid; e < 48; e += 256) {
        int sel = (e >= 32);
        int bits = sel ? (e - 32) : e;
        const int wtE[5] = {0, 2, 4, 6, 8};   // taps (0,0)(0,2)(1,1)(2,0)(2,2)
        const int wtO[4] = {1, 3, 5, 7};      // taps (0,1)(1,0)(1,2)(2,1)
        for (int ch = 0; ch < 16; ++ch) {
            float u = b0g[ch];
            if (!sel) {
                #pragma unroll
                for (int t = 0; t < 5; ++t) {
                    float s = ((bits >> t) & 1) ? 1.0f : -1.0f;
                    u = fmaf(s, w0g[wtE[t] * 16 + ch], u);
                }
            } else {
                #pragma unroll
                for (int t = 0; t < 4; ++t) {
                    float s = ((bits >> t) & 1) ? 1.0f : -1.0f;
                    u = fmaf(s, w0g[wtO[t] * 16 + ch], u);
                }
            }
            _Float16 hi, lo;
            split_f16(fast_tanh(u), hi, lo);
            ot[e * 32 + ch]      = hi;
            ot[e * 32 + 16 + ch] = lo;
        }
    }
}

__global__ __launch_bounds__(256, 4)
void discrete_flow_layer(const float* x_in,
                         float* x_out,
                         const _Float16* __restrict__ wfr,
                         const _Float16* __restrict__ tbl,
                         const float* __restrict__ b1g,
                         const float* __restrict__ w2g,
                         const float* __restrict__ b2g,
                         int parityA, int writeA)
{
    __shared__ __align__(16) _Float16 s_h1[16912];      // 20 rows x 848 f16
    __shared__ unsigned s_bits[16];                     // 22x22 sign bits
    __shared__ __align__(16) float s_w2[148];           // conv3 w (144) + b2 (1)
    float* s_h2 = (float*)s_h1;                          // [pos][20] after barrier

    const int tid  = threadIdx.x;
    const int lane = tid & 63;
    const int wv   = tid >> 6;
    const int tile = blockIdx.x;
    const int b    = blockIdx.y;
    const int r0 = (tile >> 2) * TILE;
    const int c0 = (tile & 3) * TILE;
    const float* xb = x_in + (size_t)b * (LSZ * LSZ);

    // ---- prefetch conv2 weight fragments + bias (global, L2-hot) ----
    f16x8 Bh[5], Bl[5];
    #pragma unroll
    for (int c = 0; c < 5; ++c) {
        Bh[c] = *(const f16x8*)&wfr[((c * 2 + 0) * 64 + lane) * 8];
        Bl[c] = *(const f16x8*)&wfr[((c * 2 + 1) * 64 + lane) * 8];
    }
    const float b1v = b1g[lane & 15];

    // ---- phase 0: ballot-pack masked sign bits + stage conv3 weights ----
    // bit = (A-parity) && (x > 0). R22: iter-2 indices by increment
    // (+256 = 11 rows + 14 cols), bit-exact vs the /22,%22 pair.
    if (tid < 145) s_w2[tid] = (tid < 144) ? w2g[tid] : b2g[0];   // R23
    {
        int r = tid / 22, c = tid - r * 22;
        #pragma unroll
        for (int it = 0; it < 2; ++it) {
            int idx = tid + it * 256;
            int gr = (r0 + r - 3) & 63;
            int gc = (c0 + c - 3) & 63;
            float v = xb[gr * 64 + gc];          // wrapped address, always valid
            bool bit = (idx < 484) && (((gr + gc) & 1) == parityA) && (v > 0.0f);
            unsigned long long m = __ballot(bit);
            if ((lane & 31) == 0)
                s_bits[it * 8 + wv * 2 + (lane >> 5)] = (unsigned)(m >> (lane & 32));
            r += 11; c += 14;
            if (c >= 22) { c -= 22; r += 1; }
        }
    }
    __syncthreads();

    // ---- phase 1: h1 by pattern-table lookup (index from bit array) ----
    for (int pp = tid; pp < 400; pp += 256) {
        int g  = (pp >= 200);
        int pi = pp - g * 200;
        int ry = pi / 10;
        int rx = 2 * (pi % 10) + ((ry ^ g) & 1);
        int base = ry * 22 + rx;
        int sel = g ^ parityA;
        int idx = 0;
        if (sel == 0) {                        // even-sum taps
            const int off[5] = {0, 2, 23, 44, 46};
            #pragma unroll
            for (int t = 0; t < 5; ++t) {
                int p = base + off[t];
                idx |= ((s_bits[p >> 5] >> (p & 31)) & 1) << t;
            }
        } else {                               // odd-sum taps
            const int off[4] = {1, 22, 24, 45};
            #pragma unroll
            for (int t = 0; t < 4; ++t) {
                int p = base + off[t];
                idx |= ((s_bits[p >> 5] >> (p & 31)) & 1) << t;
            }
        }
        const f16x8* row = (const f16x8*)&tbl[(sel ? 1024 : 0) + idx * 32];
        f16x8* hp = (f16x8*)&s_h1[ry * 848 + rx * 40];
        hp[0] = row[0]; hp[1] = row[1]; hp[2] = row[2]; hp[3] = row[3];
    }
    __syncthreads();

    // ---- phase 2: conv2 MFMA (M=324, N=16, K=144->160); D -> registers ----
    float Cs[6][8];
    {
        const int m0 = lane & 15, q = lane >> 4;
        const int qh = q >> 1, ql = q & 1;
        // T offsets for row pitch 848 f16 (grid step: col=+40, row=+848)
        const int T0 = 0, T1 = 40, T2 = 80, T3 = 848, T4 = 888,
                  T5 = 928, T6 = 1696, T7 = 1736, T8 = 1776, T9 = 1776;
        // div-free incremental position walk: m_abs += 64 per s (R22, exact)
        int m_lin = wv * 16 + m0;              // <= 63 at s=0
        int oyc = (m_lin >= 18) + (m_lin >= 36) + (m_lin >= 54);
        int oxc = m_lin - oyc * 18;
        #pragma unroll
        for (int s = 0; s < 6; ++s) {
            int mt = wv + s * 4;
            if (mt < 21) {
                int oy = oyc, ox = oxc;
                if (mt == 20 && m0 > 3) { oy = 17; ox = 17; }  // clamp -> 323
                int abase = oy * 848 + ox * 40 + ql * 8;
                f32x4 C0 = {0.f, 0.f, 0.f, 0.f};
                f32x4 C1 = {0.f, 0.f, 0.f, 0.f};
                int off;
                f16x8 A0, A1;
                #define CONV2_STEP(cc, TA, TB)                                        \
                    off = qh ? (TB) : (TA);                                           \
                    A0 = *(const f16x8*)&s_h1[abase + off];                           \
                    A1 = *(const f16x8*)&s_h1[abase + off + 16];                      \
                    C0 = __builtin_amdgcn_mfma_f32_16x16x32_f16(A0, Bh[cc], C0, 0, 0, 0); \
                    C1 = __builtin_amdgcn_mfma_f32_16x16x32_f16(A0, Bl[cc], C1, 0, 0, 0); \
                    C1 = __builtin_amdgcn_mfma_f32_16x16x32_f16(A1, Bh[cc], C1, 0, 0, 0);
                CONV2_STEP(0, T0, T1)
                CONV2_STEP(1, T2, T3)
                CONV2_STEP(2, T4, T5)
                CONV2_STEP(3, T6, T7)
                CONV2_STEP(4, T8, T9)
                #undef CONV2_STEP
                #pragma unroll
                for (int r = 0; r < 4; ++r) { Cs[s][r] = C0[r]; Cs[s][4 + r] = C1[r]; }
            }
            oxc += 10; oyc += 3;
            if (oxc >= 18) { oxc -= 18; oyc += 1; }
        }
    }
    __syncthreads();   // ALL h1 reads complete -> safe to overwrite (h2 alias)

    // ---- phase 3: epilogue, bit-identical h2 values, position-major f32 ----
    {
        const int m0 = lane & 15, q = lane >> 4;
        #pragma unroll
        for (int s = 0; s < 6; ++s) {
            int mt = wv + s * 4;
            if (mt < 21) {
                #pragma unroll
                for (int r = 0; r < 4; ++r) {
                    int m_out = mt * 16 + q * 4 + r;
                    if (m_out < 324) {
                        float val = Cs[s][r] + Cs[s][4 + r] * (1.0f / 2048.0f) + b1v;
                        s_h2[m_out * 20 + m0] = fast_tanh(val);
                    }
                }
            }
        }
    }
    __syncthreads();

    // ---- phase 4: conv3 at B-SITES ONLY, row-interleaved lane map ----
    // R23: weights from LDS (b128 broadcast, DS-only lgkmcnt) + 1-deep
    // prefetch of next tap's h2 float4s + early x_in load. Per-site fmaf
    // chain: tap kh-major kw-ascending, ci 0..15 ascending — exact R15
    // order, identical values -> bit-identical logits.
    if (tid < 128) {
        int pr = tid >> 4;                     // row pair 0..7
        int j4 = tid & 15;
        int ry = pr * 2 + (j4 & 1);
        int k  = j4 >> 1;                      // 0..7
        int rx = 2 * k + ((ry + parityA + 1) & 1);   // B-parity col
        int gr = r0 + ry, gc = c0 + rx;
        size_t site = (size_t)b * (LSZ * LSZ) + gr * 64 + gc;
        float xv = x_in[site];                 // early (hides under the chain)
        float acc = s_w2[144];                 // b2
        const float* hv0 = &s_h2[(ry * 18 + rx) * 20];
        float4 v0 = *(const float4*)&hv0[0];
        float4 v1 = *(const float4*)&hv0[4];
        float4 v2 = *(const float4*)&hv0[8];
        float4 v3 = *(const float4*)&hv0[12];
        #pragma unroll
        for (int tap = 0; tap < 9; ++tap) {
            float4 n0, n1, n2, n3;
            if (tap < 8) {                     // prefetch next tap's h2
                int nt = tap + 1;
                int kh = nt / 3, kw = nt % 3;  // compile-time (unrolled)
                const float* nv = &s_h2[((ry + kh) * 18 + rx + kw) * 20];
                n0 = *(const float4*)&nv[0];
                n1 = *(const float4*)&nv[4];
                n2 = *(const float4*)&nv[8];
                n3 = *(const float4*)&nv[12];
            }
            const float4 w0 = *(const float4*)&s_w2[tap * 16 + 0];
            const float4 w1 = *(const float4*)&s_w2[tap * 16 + 4];
            const float4 w2 = *(const float4*)&s_w2[tap * 16 + 8];
            const float4 w3 = *(const float4*)&s_w2[tap * 16 + 12];
            acc = fmaf(v0.x, w0.x, acc); acc = fmaf(v0.y, w0.y, acc);
            acc = fmaf(v0.z, w0.z, acc); acc = fmaf(v0.w, w0.w, acc);
            acc = fmaf(v1.x, w1.x, acc); acc = fmaf(v1.y, w1.y, acc);
            acc = fmaf(v1.z, w1.z, acc); acc = fmaf(v1.w, w1.w, acc);
            acc = fmaf(v2.x, w2.x, acc); acc = fmaf(v2.y, w2.y, acc);
            acc = fmaf(v2.z, w2.z, acc); acc = fmaf(v2.w, w2.w, acc);
            acc = fmaf(v3.x, w3.x, acc); acc = fmaf(v3.y, w3.y, acc);
            acc = fmaf(v3.z, w3.z, acc); acc = fmaf(v3.w, w3.w, acc);
            if (tap < 8) { v0 = n0; v1 = n1; v2 = n2; v3 = n3; }
        }
        float m = (acc > 0.0f) ? 1.0f : ((acc < 0.0f) ? -1.0f : 0.0f);
        x_out[site] = xv * m;
    } else if (writeA) {
        // A-site pass-through (layer 0 only)
        int t2 = tid - 128;
        int ry = t2 >> 3;
        int rx = 2 * (t2 & 7) + ((ry + parityA) & 1);        // A-parity col
        int gr = r0 + ry, gc = c0 + rx;
        size_t site = (size_t)b * (LSZ * LSZ) + gr * 64 + gc;
        x_out[site] = x_in[site];
    }
}

extern "C" void kernel_launch(void* const* d_in, const int* in_sizes, int n_in,
                              void* d_out, int out_size, void* d_ws, size_t ws_size,
                              hipStream_t stream) {
    const float* z  = (const float*)d_in[0];
    const float* W0 = (const float*)d_in[1];
    const float* B0 = (const float*)d_in[2];
    const float* W1 = (const float*)d_in[3];
    const float* B1 = (const float*)d_in[4];
    const float* W2 = (const float*)d_in[5];
    const float* B2 = (const float*)d_in[6];
    float* out = (float*)d_out;
    _Float16* ws = (_Float16*)d_ws;   // 53,248 B used

    prep<<<dim3(4), 256, 0, stream>>>(W0, B0, W1, ws);

    dim3 grid(16, 1024);
    for (int layer = 0; layer < 4; ++layer) {
        const float* xin = (layer == 0) ? z : out;
        int writeA = (layer == 0) ? 1 : 0;
        int parityA = layer & 1;
        discrete_flow_layer<<<grid, 256, 0, stream>>>(
            xin, out,
            ws + layer * 5120,
            ws + 20480 + layer * 1536,
            B1 + layer * 16,
            W2 + layer * 144,
            B2 + layer * 1,
            parityA, writeA);
    }
}

// Round 7
// 569.598 us; speedup vs baseline: 1.0361x; 1.0346x over previous
//
#include <hip/hip_runtime.h>

#define LSZ 64
#define TILE 16

typedef _Float16 f16x8 __attribute__((ext_vector_type(8)));
typedef float    f32x4 __attribute__((ext_vector_type(4)));

// LDS plan (33,888 B -> 4 blocks/CU):  [R20 address map; R24 = R22 base +
// tanh fused into phase 2 (phase 3 = stores only); R23 phase-4 changes REVERTED]
//  s_h1: 20 grid-rows x 1,696 B row pitch = 33,824 B
//        position (ry,rx) at f16 index ry*848 + rx*40 ([hi x16][lo x16][pad 8])
//        R20: +96 B/row pitch -> conv2 coset walk uniform across row wraps
//        (conflicts 2.77e7 -> 2.08e7, verified).
//        ALIASED by s_h2 (f32 position-major [pos][20], 25,920 B) after conv2;
//        R24: tanh'd values staged in registers Th[6][4] across the barrier
//        (was Cs[6][8] raw accumulators -> 24 fewer VGPR).
//  s_bits: 16 u32 = 64 B (ballot-packed sign bits, R18; absmax=0 verified)
//
// d_ws (f16): [0) conv2 K32 frags 4x5120  [20480) h1 tables 4x1536 (53,248 B)
//
// R24 THEORY: VALU is the top pipe (57%); its biggest chunk is phase-3's
//   5,184 tanh (~1,600 cyc/block) in a SERIAL post-barrier region. The
//   compiler can't hoist VALU across __syncthreads. Computing tanh at the
//   end of each s-step inside phase 2 hides it under MFMA/ds_read latency
//   (separate pipes). Same expression, same inputs -> bit-identical.
//   R23 FAILED (-4 us): phase-4 LDS-weight staging + prefetch = null ->
//   phase 4 is NOT a large fraction (occupancy deficit = ramp/imbalance).
// MFMA RULE (R21 FAILED, R7 sharpened): NEVER change the MFMA shape or
//   K-decomposition of the verified conv2 reduction (K32->K16 tail flipped
//   signs: 16-wide reduction tree != first-half of 32-wide; margins are
//   ulp-thin). Bit-identity must hold at the INSTRUCTION level.
// PERF MODEL (R19/R20/R22/R23 measured): no pipe saturated (VALU ~58%,
//   MFMA ~25%, HBM 5%); occupancy 4 vs 5 blocks/CU neutral; conflict -25%
//   -> dur -1.5%; addressing trims null; phase-4 memory restructure null.
// OCCUPANCY RULE (R11/R15/R19): __launch_bounds__ MUST stay (256,4) — the
//   2nd arg is a register-allocator FLOOR; (256,5) forced VGPR 60->48 and
//   spilled ~12 dwords/thread (R18: WRITE_SIZE 16MB->221MB, dur 148->232 us).
// COMPILER RULE (R12/R13): don't fully unroll multi-load bodies (spill).
// LAYOUT RULE (R13): h1/h2 strides must keep 16 B alignment for b128.
// NUMERICS RULE (R7): everything feeding a USED logit stays bit-identical.
// R17: phase-4 lane map row-interleaved -> conv3 b128 reads at the
// 8-touch/bank minimum.

__device__ __forceinline__ float fast_tanh(float x) {
    float ax = __builtin_fabsf(x);
    float t  = __builtin_amdgcn_exp2f(ax * -2.885390081777927f);
    float r  = (1.0f - t) * __builtin_amdgcn_rcpf(1.0f + t);
    return __builtin_copysignf(r, x);
}

__device__ __forceinline__ void split_f16(float x, _Float16& hi, _Float16& lo) {
    float h0 = (float)(_Float16)x;
    if (__builtin_fabsf(h0) < 6.104e-5f) h0 = 0.0f;
    hi = (_Float16)h0;
    lo = (_Float16)((x - h0) * 2048.0f);
}

__global__ void prep(const float* __restrict__ W0, const float* __restrict__ B0,
                     const float* __restrict__ W1, _Float16* __restrict__ ws) {
    const int layer = blockIdx.x, tid = threadIdx.x;
    const float* w1g = W1 + layer * 2304;
    _Float16* o2 = ws + layer * 5120;
    for (int e = tid; e < 320; e += 256) {
        int c = e >> 6, lane = e & 63;
        int q = lane >> 4, co = lane & 15;
        #pragma unroll
        for (int j = 0; j < 8; ++j) {
            int k = c * 32 + q * 8 + j;
            float w = (k < 144) ? w1g[k * 16 + co] : 0.0f;
            _Float16 whi, wlo;
            split_f16(w, whi, wlo);
            o2[((c * 2 + 0) * 64 + lane) * 8 + j] = whi;
            o2[((c * 2 + 1) * 64 + lane) * 8 + j] = wlo;
        }
    }
    const float* w0g = W0 + layer * 144;
    const float* b0g = B0 + layer * 16;
    _Float16* ot = ws + 20480 + layer * 1536;
    for (int e = tid; e < 48; e += 256) {
        int sel = (e >= 32);
        int bits = sel ? (e - 32) : e;
        const int wtE[5] = {0, 2, 4, 6, 8};   // taps (0,0)(0,2)(1,1)(2,0)(2,2)
        const int wtO[4] = {1, 3, 5, 7};      // taps (0,1)(1,0)(1,2)(2,1)
        for (int ch = 0; ch < 16; ++ch) {
            float u = b0g[ch];
            if (!sel) {
                #pragma unroll
                for (int t = 0; t < 5; ++t) {
                    float s = ((bits >> t) & 1) ? 1.0f : -1.0f;
                    u = fmaf(s, w0g[wtE[t] * 16 + ch], u);
                }
            } else {
                #pragma unroll
                for (int t = 0; t < 4; ++t) {
                    float s = ((bits >> t) & 1) ? 1.0f : -1.0f;
                    u = fmaf(s, w0g[wtO[t] * 16 + ch], u);
                }
            }
            _Float16 hi, lo;
            split_f16(fast_tanh(u), hi, lo);
            ot[e * 32 + ch]      = hi;
            ot[e * 32 + 16 + ch] = lo;
        }
    }
}

__global__ __launch_bounds__(256, 4)
void discrete_flow_layer(const float* x_in,
                         float* x_out,
                         const _Float16* __restrict__ wfr,
                         const _Float16* __restrict__ tbl,
                         const float* __restrict__ b1g,
                         const float* __restrict__ w2g,
                         const float* __restrict__ b2g,
                         int parityA, int writeA)
{
    __shared__ __align__(16) _Float16 s_h1[16912];      // 20 rows x 848 f16
    __shared__ unsigned s_bits[16];                     // 22x22 sign bits
    float* s_h2 = (float*)s_h1;                          // [pos][20] after barrier

    const int tid  = threadIdx.x;
    const int lane = tid & 63;
    const int wv   = tid >> 6;
    const int tile = blockIdx.x;
    const int b    = blockIdx.y;
    const int r0 = (tile >> 2) * TILE;
    const int c0 = (tile & 3) * TILE;
    const float* xb = x_in + (size_t)b * (LSZ * LSZ);

    // ---- prefetch conv2 weight fragments + bias (global, L2-hot) ----
    f16x8 Bh[5], Bl[5];
    #pragma unroll
    for (int c = 0; c < 5; ++c) {
        Bh[c] = *(const f16x8*)&wfr[((c * 2 + 0) * 64 + lane) * 8];
        Bl[c] = *(const f16x8*)&wfr[((c * 2 + 1) * 64 + lane) * 8];
    }
    const float b1v = b1g[lane & 15];

    // ---- phase 0: ballot-pack masked sign bits of the 22x22 halo tile ----
    // bit = (A-parity) && (x > 0). R22: iter-2 indices by increment
    // (+256 = 11 rows + 14 cols), bit-exact vs the /22,%22 pair.
    {
        int r = tid / 22, c = tid - r * 22;
        #pragma unroll
        for (int it = 0; it < 2; ++it) {
            int idx = tid + it * 256;
            int gr = (r0 + r - 3) & 63;
            int gc = (c0 + c - 3) & 63;
            float v = xb[gr * 64 + gc];          // wrapped address, always valid
            bool bit = (idx < 484) && (((gr + gc) & 1) == parityA) && (v > 0.0f);
            unsigned long long m = __ballot(bit);
            if ((lane & 31) == 0)
                s_bits[it * 8 + wv * 2 + (lane >> 5)] = (unsigned)(m >> (lane & 32));
            r += 11; c += 14;
            if (c >= 22) { c -= 22; r += 1; }
        }
    }
    __syncthreads();

    // ---- phase 1: h1 by pattern-table lookup (index from bit array) ----
    for (int pp = tid; pp < 400; pp += 256) {
        int g  = (pp >= 200);
        int pi = pp - g * 200;
        int ry = pi / 10;
        int rx = 2 * (pi % 10) + ((ry ^ g) & 1);
        int base = ry * 22 + rx;
        int sel = g ^ parityA;
        int idx = 0;
        if (sel == 0) {                        // even-sum taps
            const int off[5] = {0, 2, 23, 44, 46};
            #pragma unroll
            for (int t = 0; t < 5; ++t) {
                int p = base + off[t];
                idx |= ((s_bits[p >> 5] >> (p & 31)) & 1) << t;
            }
        } else {                               // odd-sum taps
            const int off[4] = {1, 22, 24, 45};
            #pragma unroll
            for (int t = 0; t < 4; ++t) {
                int p = base + off[t];
                idx |= ((s_bits[p >> 5] >> (p & 31)) & 1) << t;
            }
        }
        const f16x8* row = (const f16x8*)&tbl[(sel ? 1024 : 0) + idx * 32];
        f16x8* hp = (f16x8*)&s_h1[ry * 848 + rx * 40];
        hp[0] = row[0]; hp[1] = row[1]; hp[2] = row[2]; hp[3] = row[3];
    }
    __syncthreads();

    // ---- phase 2: conv2 MFMA (M=324, N=16, K=144->160) + FUSED tanh ----
    // R24: each s-step's epilogue (C0 + C1/2048 + b1v -> fast_tanh) runs
    // right after its MFMAs, under the next step's MFMA/ds_read latency.
    // Identical expression & inputs as the old phase 3 -> bit-identical.
    float Th[6][4];
    {
        const int m0 = lane & 15, q = lane >> 4;
        const int qh = q >> 1, ql = q & 1;
        // T offsets for row pitch 848 f16 (grid step: col=+40, row=+848)
        const int T0 = 0, T1 = 40, T2 = 80, T3 = 848, T4 = 888,
                  T5 = 928, T6 = 1696, T7 = 1736, T8 = 1776, T9 = 1776;
        // div-free incremental position walk: m_abs += 64 per s (R22, exact)
        int m_lin = wv * 16 + m0;              // <= 63 at s=0
        int oyc = (m_lin >= 18) + (m_lin >= 36) + (m_lin >= 54);
        int oxc = m_lin - oyc * 18;
        #pragma unroll
        for (int s = 0; s < 6; ++s) {
            int mt = wv + s * 4;
            if (mt < 21) {
                int oy = oyc, ox = oxc;
                if (mt == 20 && m0 > 3) { oy = 17; ox = 17; }  // clamp -> 323
                int abase = oy * 848 + ox * 40 + ql * 8;
                f32x4 C0 = {0.f, 0.f, 0.f, 0.f};
                f32x4 C1 = {0.f, 0.f, 0.f, 0.f};
                int off;
                f16x8 A0, A1;
                #define CONV2_STEP(cc, TA, TB)                                        \
                    off = qh ? (TB) : (TA);                                           \
                    A0 = *(const f16x8*)&s_h1[abase + off];                           \
                    A1 = *(const f16x8*)&s_h1[abase + off + 16];                      \
                    C0 = __builtin_amdgcn_mfma_f32_16x16x32_f16(A0, Bh[cc], C0, 0, 0, 0); \
                    C1 = __builtin_amdgcn_mfma_f32_16x16x32_f16(A0, Bl[cc], C1, 0, 0, 0); \
                    C1 = __builtin_amdgcn_mfma_f32_16x16x32_f16(A1, Bh[cc], C1, 0, 0, 0);
                CONV2_STEP(0, T0, T1)
                CONV2_STEP(1, T2, T3)
                CONV2_STEP(2, T4, T5)
                CONV2_STEP(3, T6, T7)
                CONV2_STEP(4, T8, T9)
                #undef CONV2_STEP
                #pragma unroll
                for (int r = 0; r < 4; ++r) {
                    float val = C0[r] + C1[r] * (1.0f / 2048.0f) + b1v;
                    Th[s][r] = fast_tanh(val);
                }
            }
            oxc += 10; oyc += 3;
            if (oxc >= 18) { oxc -= 18; oyc += 1; }
        }
    }
    __syncthreads();   // ALL h1 reads complete -> safe to overwrite (h2 alias)

    // ---- phase 3: pure stores of pre-computed tanh values ----
    {
        const int m0 = lane & 15, q = lane >> 4;
        #pragma unroll
        for (int s = 0; s < 6; ++s) {
            int mt = wv + s * 4;
            if (mt < 21) {
                #pragma unroll
                for (int r = 0; r < 4; ++r) {
                    int m_out = mt * 16 + q * 4 + r;
                    if (m_out < 324) {
                        s_h2[m_out * 20 + m0] = Th[s][r];
                    }
                }
            }
        }
    }
    __syncthreads();

    // ---- phase 4: conv3 at B-SITES ONLY, row-interleaved lane map ----
    // (R22 form verbatim; R23's LDS-weight/prefetch variant measured null.)
    // Consecutive lanes alternate adjacent rows -> odd p-steps -> start banks
    // cover all 8 cosets -> conv3 b128 reads at the 8-touch/bank minimum.
    // Per-site fmaf chain: tap kh-major kw-ascending, ci 0..15 ascending —
    // exact R15 order -> bit-identical logits.
    if (tid < 128) {
        int pr = tid >> 4;                     // row pair 0..7
        int j4 = tid & 15;
        int ry = pr * 2 + (j4 & 1);
        int k  = j4 >> 1;                      // 0..7
        int rx = 2 * k + ((ry + parityA + 1) & 1);   // B-parity col
        float acc = b2g[0];
        #pragma unroll
        for (int tap = 0; tap < 9; ++tap) {
            int kh = tap / 3, kw = tap % 3;
            const float* hv = &s_h2[((ry + kh) * 18 + rx + kw) * 20];
            float4 v0 = *(const float4*)&hv[0];
            float4 v1 = *(const float4*)&hv[4];
            float4 v2 = *(const float4*)&hv[8];
            float4 v3 = *(const float4*)&hv[12];
            const float* w = &w2g[tap * 16];
            acc = fmaf(v0.x, w[0],  acc); acc = fmaf(v0.y, w[1],  acc);
            acc = fmaf(v0.z, w[2],  acc); acc = fmaf(v0.w, w[3],  acc);
            acc = fmaf(v1.x, w[4],  acc); acc = fmaf(v1.y, w[5],  acc);
            acc = fmaf(v1.z, w[6],  acc); acc = fmaf(v1.w, w[7],  acc);
            acc = fmaf(v2.x, w[8],  acc); acc = fmaf(v2.y, w[9],  acc);
            acc = fmaf(v2.z, w[10], acc); acc = fmaf(v2.w, w[11], acc);
            acc = fmaf(v3.x, w[12], acc); acc = fmaf(v3.y, w[13], acc);
            acc = fmaf(v3.z, w[14], acc); acc = fmaf(v3.w, w[15], acc);
        }
        int gr = r0 + ry, gc = c0 + rx;
        size_t site = (size_t)b * (LSZ * LSZ) + gr * 64 + gc;
        float xv = x_in[site];
        float m = (acc > 0.0f) ? 1.0f : ((acc < 0.0f) ? -1.0f : 0.0f);
        x_out[site] = xv * m;
    } else if (writeA) {
        // A-site pass-through (layer 0 only)
        int t2 = tid - 128;
        int ry = t2 >> 3;
        int rx = 2 * (t2 & 7) + ((ry + parityA) & 1);        // A-parity col
        int gr = r0 + ry, gc = c0 + rx;
        size_t site = (size_t)b * (LSZ * LSZ) + gr * 64 + gc;
        x_out[site] = x_in[site];
    }
}

extern "C" void kernel_launch(void* const* d_in, const int* in_sizes, int n_in,
                              void* d_out, int out_size, void* d_ws, size_t ws_size,
                              hipStream_t stream) {
    const float* z  = (const float*)d_in[0];
    const float* W0 = (const float*)d_in[1];
    const float* B0 = (const float*)d_in[2];
    const float* W1 = (const float*)d_in[3];
    const float* B1 = (const float*)d_in[4];
    const float* W2 = (const float*)d_in[5];
    const float* B2 = (const float*)d_in[6];
    float* out = (float*)d_out;
    _Float16* ws = (_Float16*)d_ws;   // 53,248 B used

    prep<<<dim3(4), 256, 0, stream>>>(W0, B0, W1, ws);

    dim3 grid(16, 1024);
    for (int layer = 0; layer < 4; ++layer) {
        const float* xin = (layer == 0) ? z : out;
        int writeA = (layer == 0) ? 1 : 0;
        int parityA = layer & 1;
        discrete_flow_layer<<<grid, 256, 0, stream>>>(
            xin, out,
            ws + layer * 5120,
            ws + 20480 + layer * 1536,
            B1 + layer * 16,
            W2 + layer * 144,
            B2 + layer * 1,
            parityA, writeA);
    }
}

// Round 8
// 557.967 us; speedup vs baseline: 1.0577x; 1.0208x over previous
//
#include <hip/hip_runtime.h>

#define LSZ 64
#define TILE 16

typedef _Float16 f16x8 __attribute__((ext_vector_type(8)));
typedef float    f32x4 __attribute__((ext_vector_type(4)));

// LDS plan (33,888 B -> 4 blocks/CU):  [R24 structure + R25 XCD swizzle]
//  s_h1: 20 grid-rows x 1,696 B row pitch = 33,824 B
//        position (ry,rx) at f16 index ry*848 + rx*40 ([hi x16][lo x16][pad 8])
//        R20: +96 B/row pitch -> conv2 coset walk uniform across row wraps
//        (conflicts 2.77e7 -> 2.08e7, verified).
//        ALIASED by s_h2 (f32 position-major [pos][20], 25,920 B) after conv2;
//        R24: tanh fused into phase 2 (Th[6][4] across barrier, VGPR 60->52,
//        -2 us verified); phase 3 = pure stores.
//  s_bits: 16 u32 = 64 B (ballot-packed sign bits, R18; absmax=0 verified)
//
// d_ws (f16): [0) conv2 K32 frags 4x5120  [20480) h1 tables 4x1536 (53,248 B)
//
// R25 THEORY: FETCH 45 MB vs 16 MB unique x. Grid (16,1024) x-major ->
//   the 16 tiles of a batch round-robin across 8 XCDs (HW n%8 model, T1)
//   -> halo rows fetched into up to 8 non-coherent L2s (~2.8x over-fetch)
//   and layer l+1 reads x from the wrong XCD's L2. Fix: bijective remap
//   n -> (xcd=n&7, tile=(n>>3)&15, batch=(n&7)*128 + (n>>7)) so all 16
//   tiles of a batch share one XCD, adjacent in time, layer-invariant.
//   Pure work permutation -> bit-identical output.
// MFMA RULE (R21 FAILED, R7 sharpened): NEVER change the MFMA shape or
//   K-decomposition of the verified conv2 reduction (K32->K16 tail flipped
//   signs: margins are ulp-thin). Bit-identity at the INSTRUCTION level.
// PERF MODEL (R19-R24 measured, corrected MFMA cost 19.4 SIMD-cyc/instr):
//   per CU-generation ~21.5k cyc: LDS ~74% (dominant but with slack),
//   VALU ~19%+MFMA issue, MFMA 28%; occupancy 4 vs 5 blocks/CU neutral
//   (twice); conflict -25% -> dur -1.5%; phase-4 restructure null; tanh
//   fusion -2 us. Latency/overlap regime; global path untested until R25.
// OCCUPANCY RULE (R11/R15/R19): __launch_bounds__ MUST stay (256,4) — the
//   2nd arg is a register-allocator FLOOR; (256,5) forced VGPR 60->48 and
//   spilled ~12 dwords/thread (R18: WRITE_SIZE 16MB->221MB, dur 148->232 us).
// COMPILER RULE (R12/R13): don't fully unroll multi-load bodies (spill).
// LAYOUT RULE (R13): h1/h2 strides must keep 16 B alignment for b128.
// NUMERICS RULE (R7): everything feeding a USED logit stays bit-identical.
// R17: phase-4 lane map row-interleaved -> conv3 b128 reads at the
// 8-touch/bank minimum.

__device__ __forceinline__ float fast_tanh(float x) {
    float ax = __builtin_fabsf(x);
    float t  = __builtin_amdgcn_exp2f(ax * -2.885390081777927f);
    float r  = (1.0f - t) * __builtin_amdgcn_rcpf(1.0f + t);
    return __builtin_copysignf(r, x);
}

__device__ __forceinline__ void split_f16(float x, _Float16& hi, _Float16& lo) {
    float h0 = (float)(_Float16)x;
    if (__builtin_fabsf(h0) < 6.104e-5f) h0 = 0.0f;
    hi = (_Float16)h0;
    lo = (_Float16)((x - h0) * 2048.0f);
}

__global__ void prep(const float* __restrict__ W0, const float* __restrict__ B0,
                     const float* __restrict__ W1, _Float16* __restrict__ ws) {
    const int layer = blockIdx.x, tid = threadIdx.x;
    const float* w1g = W1 + layer * 2304;
    _Float16* o2 = ws + layer * 5120;
    for (int e = tid; e < 320; e += 256) {
        int c = e >> 6, lane = e & 63;
        int q = lane >> 4, co = lane & 15;
        #pragma unroll
        for (int j = 0; j < 8; ++j) {
            int k = c * 32 + q * 8 + j;
            float w = (k < 144) ? w1g[k * 16 + co] : 0.0f;
            _Float16 whi, wlo;
            split_f16(w, whi, wlo);
            o2[((c * 2 + 0) * 64 + lane) * 8 + j] = whi;
            o2[((c * 2 + 1) * 64 + lane) * 8 + j] = wlo;
        }
    }
    const float* w0g = W0 + layer * 144;
    const float* b0g = B0 + layer * 16;
    _Float16* ot = ws + 20480 + layer * 1536;
    for (int e = tid; e < 48; e += 256) {
        int sel = (e >= 32);
        int bits = sel ? (e - 32) : e;
        const int wtE[5] = {0, 2, 4, 6, 8};   // taps (0,0)(0,2)(1,1)(2,0)(2,2)
        const int wtO[4] = {1, 3, 5, 7};      // taps (0,1)(1,0)(1,2)(2,1)
        for (int ch = 0; ch < 16; ++ch) {
            float u = b0g[ch];
            if (!sel) {
                #pragma unroll
                for (int t = 0; t < 5; ++t) {
                    float s = ((bits >> t) & 1) ? 1.0f : -1.0f;
                    u = fmaf(s, w0g[wtE[t] * 16 + ch], u);
                }
            } else {
                #pragma unroll
                for (int t = 0; t < 4; ++t) {
                    float s = ((bits >> t) & 1) ? 1.0f : -1.0f;
                    u = fmaf(s, w0g[wtO[t] * 16 + ch], u);
                }
            }
            _Float16 hi, lo;
            split_f16(fast_tanh(u), hi, lo);
            ot[e * 32 + ch]      = hi;
            ot[e * 32 + 16 + ch] = lo;
        }
    }
}

__global__ __launch_bounds__(256, 4)
void discrete_flow_layer(const float* x_in,
                         float* x_out,
                         const _Float16* __restrict__ wfr,
                         const _Float16* __restrict__ tbl,
                         const float* __restrict__ b1g,
                         const float* __restrict__ w2g,
                         const float* __restrict__ b2g,
                         int parityA, int writeA)
{
    __shared__ __align__(16) _Float16 s_h1[16912];      // 20 rows x 848 f16
    __shared__ unsigned s_bits[16];                     // 22x22 sign bits
    float* s_h2 = (float*)s_h1;                          // [pos][20] after barrier

    const int tid  = threadIdx.x;
    const int lane = tid & 63;
    const int wv   = tid >> 6;
    // R25: XCD-affinity remap. HW assigns workgroup n -> XCD (n % 8)
    // (round-robin model, T1). Map so all 16 tiles of a batch share one
    // XCD and are adjacent in time; layer-invariant -> cross-layer L2 hits.
    const int n    = blockIdx.y * 16 + blockIdx.x;      // dispatch-linear id
    const int slot = n >> 3;
    const int tile = slot & 15;
    const int b    = (n & 7) * 128 + (slot >> 4);
    const int r0 = (tile >> 2) * TILE;
    const int c0 = (tile & 3) * TILE;
    const float* xb = x_in + (size_t)b * (LSZ * LSZ);

    // ---- prefetch conv2 weight fragments + bias (global, L2-hot) ----
    f16x8 Bh[5], Bl[5];
    #pragma unroll
    for (int c = 0; c < 5; ++c) {
        Bh[c] = *(const f16x8*)&wfr[((c * 2 + 0) * 64 + lane) * 8];
        Bl[c] = *(const f16x8*)&wfr[((c * 2 + 1) * 64 + lane) * 8];
    }
    const float b1v = b1g[lane & 15];

    // ---- phase 0: ballot-pack masked sign bits of the 22x22 halo tile ----
    // bit = (A-parity) && (x > 0). R22: iter-2 indices by increment
    // (+256 = 11 rows + 14 cols), bit-exact vs the /22,%22 pair.
    {
        int r = tid / 22, c = tid - r * 22;
        #pragma unroll
        for (int it = 0; it < 2; ++it) {
            int idx = tid + it * 256;
            int gr = (r0 + r - 3) & 63;
            int gc = (c0 + c - 3) & 63;
            float v = xb[gr * 64 + gc];          // wrapped address, always valid
            bool bit = (idx < 484) && (((gr + gc) & 1) == parityA) && (v > 0.0f);
            unsigned long long m = __ballot(bit);
            if ((lane & 31) == 0)
                s_bits[it * 8 + wv * 2 + (lane >> 5)] = (unsigned)(m >> (lane & 32));
            r += 11; c += 14;
            if (c >= 22) { c -= 22; r += 1; }
        }
    }
    __syncthreads();

    // ---- phase 1: h1 by pattern-table lookup (index from bit array) ----
    for (int pp = tid; pp < 400; pp += 256) {
        int g  = (pp >= 200);
        int pi = pp - g * 200;
        int ry = pi / 10;
        int rx = 2 * (pi % 10) + ((ry ^ g) & 1);
        int base = ry * 22 + rx;
        int sel = g ^ parityA;
        int idx = 0;
        if (sel == 0) {                        // even-sum taps
            const int off[5] = {0, 2, 23, 44, 46};
            #pragma unroll
            for (int t = 0; t < 5; ++t) {
                int p = base + off[t];
                idx |= ((s_bits[p >> 5] >> (p & 31)) & 1) << t;
            }
        } else {                               // odd-sum taps
            const int off[4] = {1, 22, 24, 45};
            #pragma unroll
            for (int t = 0; t < 4; ++t) {
                int p = base + off[t];
                idx |= ((s_bits[p >> 5] >> (p & 31)) & 1) << t;
            }
        }
        const f16x8* row = (const f16x8*)&tbl[(sel ? 1024 : 0) + idx * 32];
        f16x8* hp = (f16x8*)&s_h1[ry * 848 + rx * 40];
        hp[0] = row[0]; hp[1] = row[1]; hp[2] = row[2]; hp[3] = row[3];
    }
    __syncthreads();

    // ---- phase 2: conv2 MFMA (M=324, N=16, K=144->160) + FUSED tanh ----
    // R24: each s-step's epilogue (C0 + C1/2048 + b1v -> fast_tanh) runs
    // right after its MFMAs, under the next step's MFMA/ds_read latency.
    // Identical expression & inputs as the old phase 3 -> bit-identical.
    float Th[6][4];
    {
        const int m0 = lane & 15, q = lane >> 4;
        const int qh = q >> 1, ql = q & 1;
        // T offsets for row pitch 848 f16 (grid step: col=+40, row=+848)
        const int T0 = 0, T1 = 40, T2 = 80, T3 = 848, T4 = 888,
                  T5 = 928, T6 = 1696, T7 = 1736, T8 = 1776, T9 = 1776;
        // div-free incremental position walk: m_abs += 64 per s (R22, exact)
        int m_lin = wv * 16 + m0;              // <= 63 at s=0
        int oyc = (m_lin >= 18) + (m_lin >= 36) + (m_lin >= 54);
        int oxc = m_lin - oyc * 18;
        #pragma unroll
        for (int s = 0; s < 6; ++s) {
            int mt = wv + s * 4;
            if (mt < 21) {
                int oy = oyc, ox = oxc;
                if (mt == 20 && m0 > 3) { oy = 17; ox = 17; }  // clamp -> 323
                int abase = oy * 848 + ox * 40 + ql * 8;
                f32x4 C0 = {0.f, 0.f, 0.f, 0.f};
                f32x4 C1 = {0.f, 0.f, 0.f, 0.f};
                int off;
                f16x8 A0, A1;
                #define CONV2_STEP(cc, TA, TB)                                        \
                    off = qh ? (TB) : (TA);                                           \
                    A0 = *(const f16x8*)&s_h1[abase + off];                           \
                    A1 = *(const f16x8*)&s_h1[abase + off + 16];                      \
                    C0 = __builtin_amdgcn_mfma_f32_16x16x32_f16(A0, Bh[cc], C0, 0, 0, 0); \
                    C1 = __builtin_amdgcn_mfma_f32_16x16x32_f16(A0, Bl[cc], C1, 0, 0, 0); \
                    C1 = __builtin_amdgcn_mfma_f32_16x16x32_f16(A1, Bh[cc], C1, 0, 0, 0);
                CONV2_STEP(0, T0, T1)
                CONV2_STEP(1, T2, T3)
                CONV2_STEP(2, T4, T5)
                CONV2_STEP(3, T6, T7)
                CONV2_STEP(4, T8, T9)
                #undef CONV2_STEP
                #pragma unroll
                for (int r = 0; r < 4; ++r) {
                    float val = C0[r] + C1[r] * (1.0f / 2048.0f) + b1v;
                    Th[s][r] = fast_tanh(val);
                }
            }
            oxc += 10; oyc += 3;
            if (oxc >= 18) { oxc -= 18; oyc += 1; }
        }
    }
    __syncthreads();   // ALL h1 reads complete -> safe to overwrite (h2 alias)

    // ---- phase 3: pure stores of pre-computed tanh values ----
    {
        const int m0 = lane & 15, q = lane >> 4;
        #pragma unroll
        for (int s = 0; s < 6; ++s) {
            int mt = wv + s * 4;
            if (mt < 21) {
                #pragma unroll
                for (int r = 0; r < 4; ++r) {
                    int m_out = mt * 16 + q * 4 + r;
                    if (m_out < 324) {
                        s_h2[m_out * 20 + m0] = Th[s][r];
                    }
                }
            }
        }
    }
    __syncthreads();

    // ---- phase 4: conv3 at B-SITES ONLY, row-interleaved lane map ----
    // (R22 form verbatim; R23's LDS-weight/prefetch variant measured null.)
    // Consecutive lanes alternate adjacent rows -> odd p-steps -> start banks
    // cover all 8 cosets -> conv3 b128 reads at the 8-touch/bank minimum.
    // Per-site fmaf chain: tap kh-major kw-ascending, ci 0..15 ascending —
    // exact R15 order -> bit-identical logits.
    if (tid < 128) {
        int pr = tid >> 4;                     // row pair 0..7
        int j4 = tid & 15;
        int ry = pr * 2 + (j4 & 1);
        int k  = j4 >> 1;                      // 0..7
        int rx = 2 * k + ((ry + parityA + 1) & 1);   // B-parity col
        float acc = b2g[0];
        #pragma unroll
        for (int tap = 0; tap < 9; ++tap) {
            int kh = tap / 3, kw = tap % 3;
            const float* hv = &s_h2[((ry + kh) * 18 + rx + kw) * 20];
            float4 v0 = *(const float4*)&hv[0];
            float4 v1 = *(const float4*)&hv[4];
            float4 v2 = *(const float4*)&hv[8];
            float4 v3 = *(const float4*)&hv[12];
            const float* w = &w2g[tap * 16];
            acc = fmaf(v0.x, w[0],  acc); acc = fmaf(v0.y, w[1],  acc);
            acc = fmaf(v0.z, w[2],  acc); acc = fmaf(v0.w, w[3],  acc);
            acc = fmaf(v1.x, w[4],  acc); acc = fmaf(v1.y, w[5],  acc);
            acc = fmaf(v1.z, w[6],  acc); acc = fmaf(v1.w, w[7],  acc);
            acc = fmaf(v2.x, w[8],  acc); acc = fmaf(v2.y, w[9],  acc);
            acc = fmaf(v2.z, w[10], acc); acc = fmaf(v2.w, w[11], acc);
            acc = fmaf(v3.x, w[12], acc); acc = fmaf(v3.y, w[13], acc);
            acc = fmaf(v3.z, w[14], acc); acc = fmaf(v3.w, w[15], acc);
        }
        int gr = r0 + ry, gc = c0 + rx;
        size_t site = (size_t)b * (LSZ * LSZ) + gr * 64 + gc;
        float xv = x_in[site];
        float m = (acc > 0.0f) ? 1.0f : ((acc < 0.0f) ? -1.0f : 0.0f);
        x_out[site] = xv * m;
    } else if (writeA) {
        // A-site pass-through (layer 0 only)
        int t2 = tid - 128;
        int ry = t2 >> 3;
        int rx = 2 * (t2 & 7) + ((ry + parityA) & 1);        // A-parity col
        int gr = r0 + ry, gc = c0 + rx;
        size_t site = (size_t)b * (LSZ * LSZ) + gr * 64 + gc;
        x_out[site] = x_in[site];
    }
}

extern "C" void kernel_launch(void* const* d_in, const int* in_sizes, int n_in,
                              void* d_out, int out_size, void* d_ws, size_t ws_size,
                              hipStream_t stream) {
    const float* z  = (const float*)d_in[0];
    const float* W0 = (const float*)d_in[1];
    const float* B0 = (const float*)d_in[2];
    const float* W1 = (const float*)d_in[3];
    const float* B1 = (const float*)d_in[4];
    const float* W2 = (const float*)d_in[5];
    const float* B2 = (const float*)d_in[6];
    float* out = (float*)d_out;
    _Float16* ws = (_Float16*)d_ws;   // 53,248 B used

    prep<<<dim3(4), 256, 0, stream>>>(W0, B0, W1, ws);

    dim3 grid(16, 1024);
    for (int layer = 0; layer < 4; ++layer) {
        const float* xin = (layer == 0) ? z : out;
        int writeA = (layer == 0) ? 1 : 0;
        int parityA = layer & 1;
        discrete_flow_layer<<<grid, 256, 0, stream>>>(
            xin, out,
            ws + layer * 5120,
            ws + 20480 + layer * 1536,
            B1 + layer * 16,
            W2 + layer * 144,
            B2 + layer * 1,
            parityA, writeA);
    }
}

// Round 9
// 551.830 us; speedup vs baseline: 1.0695x; 1.0111x over previous
//
#include <hip/hip_runtime.h>

#define LSZ 64
#define TILE 16

typedef _Float16 f16x8 __attribute__((ext_vector_type(8)));
typedef float    f32x4 __attribute__((ext_vector_type(4)));

// LDS plan (~37.9 KB -> 4 blocks/CU):  [R25 structure + R26 table-in-LDS]
//  s_h1: 20 grid-rows x 1,696 B row pitch = 33,824 B
//        position (ry,rx) at f16 index ry*848 + rx*40 ([hi x16][lo x16][pad 8])
//        R20: +96 B/row pitch -> conv2 coset walk uniform across row wraps
//        (conflicts 2.77e7 -> 2.08e7, verified).
//        ALIASED by s_h2 (f32 position-major [pos][20], 25,920 B) after conv2;
//        R24: tanh fused into phase 2 (Th[6][4], VGPR 60->52, -2 us).
//  s_bits: 16 u32 = 64 B (ballot-packed sign bits, R18)
//  s_tbl: 48 rows x 80 B pitch = 3,840 B (R26). The per-layer h1 table is
//        3 KB contiguous (48 x 64 B); phase-1 read it as 25 wave-gathers of
//        64 DISTINCT lines each (~6,400 TA-cyc/CU-generation, ~30% of the
//        21.3k budget, invisible to FETCH/VALU counters). Staged to LDS
//        with 80 B pitch (20 words ≡ 20 mod 32 -> 8 bank cosets) the same
//        reads cost ~1,200 LDS-cyc/gen. Bit-copied -> absmax 0 guaranteed.
//
// d_ws (f16): [0) conv2 K32 frags 4x5120  [20480) h1 tables 4x1536 (53,248 B)
//
// R25 (verified): XCD-affinity remap (n&7 -> same XCD for a batch's 16
//   tiles) cut FETCH 45.2 -> 8.3 MB; dur -1.3 us (fetch not critical-path).
// MFMA RULE (R21 FAILED, R7 sharpened): NEVER change the MFMA shape or
//   K-decomposition of the verified conv2 reduction (K32->K16 tail flipped
//   signs: margins are ulp-thin). Bit-identity at the INSTRUCTION level.
// PERF MODEL (R19-R25 measured): no pipe saturated; LDS busiest (~78% est);
//   occupancy 4 vs 5 blocks/CU neutral (x2); conflicts -25% -> -1.5%;
//   VALU trims null; phase-4 restructure null; tanh fusion -2 us; global
//   -5.4x traffic -> -1 us. TA gather path is the LAST unprobed pipe (R26).
// OCCUPANCY RULE (R11/R15/R19): __launch_bounds__ MUST stay (256,4) — the
//   2nd arg is a register-allocator FLOOR; (256,5) forced VGPR 60->48 and
//   spilled ~12 dwords/thread (R18: WRITE_SIZE 16MB->221MB, dur 148->232 us).
// COMPILER RULE (R12/R13): don't fully unroll multi-load bodies (spill).
// LAYOUT RULE (R13): h1/h2/tbl strides must keep 16 B alignment for b128.
// NUMERICS RULE (R7): everything feeding a USED logit stays bit-identical.
// R17: phase-4 lane map row-interleaved -> conv3 b128 reads at the
// 8-touch/bank minimum.

__device__ __forceinline__ float fast_tanh(float x) {
    float ax = __builtin_fabsf(x);
    float t  = __builtin_amdgcn_exp2f(ax * -2.885390081777927f);
    float r  = (1.0f - t) * __builtin_amdgcn_rcpf(1.0f + t);
    return __builtin_copysignf(r, x);
}

__device__ __forceinline__ void split_f16(float x, _Float16& hi, _Float16& lo) {
    float h0 = (float)(_Float16)x;
    if (__builtin_fabsf(h0) < 6.104e-5f) h0 = 0.0f;
    hi = (_Float16)h0;
    lo = (_Float16)((x - h0) * 2048.0f);
}

__global__ void prep(const float* __restrict__ W0, const float* __restrict__ B0,
                     const float* __restrict__ W1, _Float16* __restrict__ ws) {
    const int layer = blockIdx.x, tid = threadIdx.x;
    const float* w1g = W1 + layer * 2304;
    _Float16* o2 = ws + layer * 5120;
    for (int e = tid; e < 320; e += 256) {
        int c = e >> 6, lane = e & 63;
        int q = lane >> 4, co = lane & 15;
        #pragma unroll
        for (int j = 0; j < 8; ++j) {
            int k = c * 32 + q * 8 + j;
            float w = (k < 144) ? w1g[k * 16 + co] : 0.0f;
            _Float16 whi, wlo;
            split_f16(w, whi, wlo);
            o2[((c * 2 + 0) * 64 + lane) * 8 + j] = whi;
            o2[((c * 2 + 1) * 64 + lane) * 8 + j] = wlo;
        }
    }
    const float* w0g = W0 + layer * 144;
    const float* b0g = B0 + layer * 16;
    _Float16* ot = ws + 20480 + layer * 1536;
    for (int e = tid; e < 48; e += 256) {
        int sel = (e >= 32);
        int bits = sel ? (e - 32) : e;
        const int wtE[5] = {0, 2, 4, 6, 8};   // taps (0,0)(0,2)(1,1)(2,0)(2,2)
        const int wtO[4] = {1, 3, 5, 7};      // taps (0,1)(1,0)(1,2)(2,1)
        for (int ch = 0; ch < 16; ++ch) {
            float u = b0g[ch];
            if (!sel) {
                #pragma unroll
                for (int t = 0; t < 5; ++t) {
                    float s = ((bits >> t) & 1) ? 1.0f : -1.0f;
                    u = fmaf(s, w0g[wtE[t] * 16 + ch], u);
                }
            } else {
                #pragma unroll
                for (int t = 0; t < 4; ++t) {
                    float s = ((bits >> t) & 1) ? 1.0f : -1.0f;
                    u = fmaf(s, w0g[wtO[t] * 16 + ch], u);
                }
            }
            _Float16 hi, lo;
            split_f16(fast_tanh(u), hi, lo);
            ot[e * 32 + ch]      = hi;
            ot[e * 32 + 16 + ch] = lo;
        }
    }
}

__global__ __launch_bounds__(256, 4)
void discrete_flow_layer(const float* x_in,
                         float* x_out,
                         const _Float16* __restrict__ wfr,
                         const _Float16* __restrict__ tbl,
                         const float* __restrict__ b1g,
                         const float* __restrict__ w2g,
                         const float* __restrict__ b2g,
                         int parityA, int writeA)
{
    __shared__ __align__(16) _Float16 s_h1[16912];      // 20 rows x 848 f16
    __shared__ unsigned s_bits[16];                     // 22x22 sign bits
    __shared__ __align__(16) _Float16 s_tbl[48 * 40];   // R26: table, 80B pitch
    float* s_h2 = (float*)s_h1;                          // [pos][20] after barrier

    const int tid  = threadIdx.x;
    const int lane = tid & 63;
    const int wv   = tid >> 6;
    // R25: XCD-affinity remap (verified: FETCH 45.2 -> 8.3 MB). HW assigns
    // workgroup n -> XCD (n % 8); map so all 16 tiles of a batch share one
    // XCD, adjacent in time, layer-invariant -> cross-layer L2 hits.
    const int n    = blockIdx.y * 16 + blockIdx.x;      // dispatch-linear id
    const int slot = n >> 3;
    const int tile = slot & 15;
    const int b    = (n & 7) * 128 + (slot >> 4);
    const int r0 = (tile >> 2) * TILE;
    const int c0 = (tile & 3) * TILE;
    const float* xb = x_in + (size_t)b * (LSZ * LSZ);

    // ---- prefetch conv2 weight fragments + bias (global, L2-hot) ----
    f16x8 Bh[5], Bl[5];
    #pragma unroll
    for (int c = 0; c < 5; ++c) {
        Bh[c] = *(const f16x8*)&wfr[((c * 2 + 0) * 64 + lane) * 8];
        Bl[c] = *(const f16x8*)&wfr[((c * 2 + 1) * 64 + lane) * 8];
    }
    const float b1v = b1g[lane & 15];

    // ---- phase 0: ballot-pack sign bits + stage h1 table to LDS ----
    // bit = (A-parity) && (x > 0). R22: iter-2 indices by increment
    // (+256 = 11 rows + 14 cols), bit-exact vs the /22,%22 pair.
    {
        int r = tid / 22, c = tid - r * 22;
        #pragma unroll
        for (int it = 0; it < 2; ++it) {
            int idx = tid + it * 256;
            int gr = (r0 + r - 3) & 63;
            int gc = (c0 + c - 3) & 63;
            float v = xb[gr * 64 + gc];          // wrapped address, always valid
            bool bit = (idx < 484) && (((gr + gc) & 1) == parityA) && (v > 0.0f);
            unsigned long long m = __ballot(bit);
            if ((lane & 31) == 0)
                s_bits[it * 8 + wv * 2 + (lane >> 5)] = (unsigned)(m >> (lane & 32));
            r += 11; c += 14;
            if (c >= 22) { c -= 22; r += 1; }
        }
    }
    // R26: stage the 48x64B table (contiguous: sel1 base 1024 = row 32).
    // Coalesced global reads; LDS row pitch 40 f16 = 80 B (8 bank cosets).
    if (tid < 48) {
        const f16x8* src = (const f16x8*)&tbl[tid * 32];
        f16x8* dst = (f16x8*)&s_tbl[tid * 40];
        dst[0] = src[0]; dst[1] = src[1]; dst[2] = src[2]; dst[3] = src[3];
    }
    __syncthreads();

    // ---- phase 1: h1 by pattern-table lookup (bits + LDS table) ----
    for (int pp = tid; pp < 400; pp += 256) {
        int g  = (pp >= 200);
        int pi = pp - g * 200;
        int ry = pi / 10;
        int rx = 2 * (pi % 10) + ((ry ^ g) & 1);
        int base = ry * 22 + rx;
        int sel = g ^ parityA;
        int idx = 0;
        if (sel == 0) {                        // even-sum taps
            const int off[5] = {0, 2, 23, 44, 46};
            #pragma unroll
            for (int t = 0; t < 5; ++t) {
                int p = base + off[t];
                idx |= ((s_bits[p >> 5] >> (p & 31)) & 1) << t;
            }
        } else {                               // odd-sum taps
            const int off[4] = {1, 22, 24, 45};
            #pragma unroll
            for (int t = 0; t < 4; ++t) {
                int p = base + off[t];
                idx |= ((s_bits[p >> 5] >> (p & 31)) & 1) << t;
            }
        }
        const f16x8* row = (const f16x8*)&s_tbl[((sel << 5) + idx) * 40];
        f16x8* hp = (f16x8*)&s_h1[ry * 848 + rx * 40];
        hp[0] = row[0]; hp[1] = row[1]; hp[2] = row[2]; hp[3] = row[3];
    }
    __syncthreads();

    // ---- phase 2: conv2 MFMA (M=324, N=16, K=144->160) + FUSED tanh ----
    // R24: each s-step's epilogue (C0 + C1/2048 + b1v -> fast_tanh) runs
    // right after its MFMAs, under the next step's MFMA/ds_read latency.
    // Identical expression & inputs as the old phase 3 -> bit-identical.
    float Th[6][4];
    {
        const int m0 = lane & 15, q = lane >> 4;
        const int qh = q >> 1, ql = q & 1;
        // T offsets for row pitch 848 f16 (grid step: col=+40, row=+848)
        const int T0 = 0, T1 = 40, T2 = 80, T3 = 848, T4 = 888,
                  T5 = 928, T6 = 1696, T7 = 1736, T8 = 1776, T9 = 1776;
        // div-free incremental position walk: m_abs += 64 per s (R22, exact)
        int m_lin = wv * 16 + m0;              // <= 63 at s=0
        int oyc = (m_lin >= 18) + (m_lin >= 36) + (m_lin >= 54);
        int oxc = m_lin - oyc * 18;
        #pragma unroll
        for (int s = 0; s < 6; ++s) {
            int mt = wv + s * 4;
            if (mt < 21) {
                int oy = oyc, ox = oxc;
                if (mt == 20 && m0 > 3) { oy = 17; ox = 17; }  // clamp -> 323
                int abase = oy * 848 + ox * 40 + ql * 8;
                f32x4 C0 = {0.f, 0.f, 0.f, 0.f};
                f32x4 C1 = {0.f, 0.f, 0.f, 0.f};
                int off;
                f16x8 A0, A1;
                #define CONV2_STEP(cc, TA, TB)                                        \
                    off = qh ? (TB) : (TA);                                           \
                    A0 = *(const f16x8*)&s_h1[abase + off];                           \
                    A1 = *(const f16x8*)&s_h1[abase + off + 16];                      \
                    C0 = __builtin_amdgcn_mfma_f32_16x16x32_f16(A0, Bh[cc], C0, 0, 0, 0); \
                    C1 = __builtin_amdgcn_mfma_f32_16x16x32_f16(A0, Bl[cc], C1, 0, 0, 0); \
                    C1 = __builtin_amdgcn_mfma_f32_16x16x32_f16(A1, Bh[cc], C1, 0, 0, 0);
                CONV2_STEP(0, T0, T1)
                CONV2_STEP(1, T2, T3)
                CONV2_STEP(2, T4, T5)
                CONV2_STEP(3, T6, T7)
                CONV2_STEP(4, T8, T9)
                #undef CONV2_STEP
                #pragma unroll
                for (int r = 0; r < 4; ++r) {
                    float val = C0[r] + C1[r] * (1.0f / 2048.0f) + b1v;
                    Th[s][r] = fast_tanh(val);
                }
            }
            oxc += 10; oyc += 3;
            if (oxc >= 18) { oxc -= 18; oyc += 1; }
        }
    }
    __syncthreads();   // ALL h1 reads complete -> safe to overwrite (h2 alias)

    // ---- phase 3: pure stores of pre-computed tanh values ----
    {
        const int m0 = lane & 15, q = lane >> 4;
        #pragma unroll
        for (int s = 0; s < 6; ++s) {
            int mt = wv + s * 4;
            if (mt < 21) {
                #pragma unroll
                for (int r = 0; r < 4; ++r) {
                    int m_out = mt * 16 + q * 4 + r;
                    if (m_out < 324) {
                        s_h2[m_out * 20 + m0] = Th[s][r];
                    }
                }
            }
        }
    }
    __syncthreads();

    // ---- phase 4: conv3 at B-SITES ONLY, row-interleaved lane map ----
    // (R22 form verbatim; R23's LDS-weight/prefetch variant measured null.)
    // Consecutive lanes alternate adjacent rows -> odd p-steps -> start banks
    // cover all 8 cosets -> conv3 b128 reads at the 8-touch/bank minimum.
    // Per-site fmaf chain: tap kh-major kw-ascending, ci 0..15 ascending —
    // exact R15 order -> bit-identical logits.
    if (tid < 128) {
        int pr = tid >> 4;                     // row pair 0..7
        int j4 = tid & 15;
        int ry = pr * 2 + (j4 & 1);
        int k  = j4 >> 1;                      // 0..7
        int rx = 2 * k + ((ry + parityA + 1) & 1);   // B-parity col
        float acc = b2g[0];
        #pragma unroll
        for (int tap = 0; tap < 9; ++tap) {
            int kh = tap / 3, kw = tap % 3;
            const float* hv = &s_h2[((ry + kh) * 18 + rx + kw) * 20];
            float4 v0 = *(const float4*)&hv[0];
            float4 v1 = *(const float4*)&hv[4];
            float4 v2 = *(const float4*)&hv[8];
            float4 v3 = *(const float4*)&hv[12];
            const float* w = &w2g[tap * 16];
            acc = fmaf(v0.x, w[0],  acc); acc = fmaf(v0.y, w[1],  acc);
            acc = fmaf(v0.z, w[2],  acc); acc = fmaf(v0.w, w[3],  acc);
            acc = fmaf(v1.x, w[4],  acc); acc = fmaf(v1.y, w[5],  acc);
            acc = fmaf(v1.z, w[6],  acc); acc = fmaf(v1.w, w[7],  acc);
            acc = fmaf(v2.x, w[8],  acc); acc = fmaf(v2.y, w[9],  acc);
            acc = fmaf(v2.z, w[10], acc); acc = fmaf(v2.w, w[11], acc);
            acc = fmaf(v3.x, w[12], acc); acc = fmaf(v3.y, w[13], acc);
            acc = fmaf(v3.z, w[14], acc); acc = fmaf(v3.w, w[15], acc);
        }
        int gr = r0 + ry, gc = c0 + rx;
        size_t site = (size_t)b * (LSZ * LSZ) + gr * 64 + gc;
        float xv = x_in[site];
        float m = (acc > 0.0f) ? 1.0f : ((acc < 0.0f) ? -1.0f : 0.0f);
        x_out[site] = xv * m;
    } else if (writeA) {
        // A-site pass-through (layer 0 only)
        int t2 = tid - 128;
        int ry = t2 >> 3;
        int rx = 2 * (t2 & 7) + ((ry + parityA) & 1);        // A-parity col
        int gr = r0 + ry, gc = c0 + rx;
        size_t site = (size_t)b * (LSZ * LSZ) + gr * 64 + gc;
        x_out[site] = x_in[site];
    }
}

extern "C" void kernel_launch(void* const* d_in, const int* in_sizes, int n_in,
                              void* d_out, int out_size, void* d_ws, size_t ws_size,
                              hipStream_t stream) {
    const float* z  = (const float*)d_in[0];
    const float* W0 = (const float*)d_in[1];
    const float* B0 = (const float*)d_in[2];
    const float* W1 = (const float*)d_in[3];
    const float* B1 = (const float*)d_in[4];
    const float* W2 = (const float*)d_in[5];
    const float* B2 = (const float*)d_in[6];
    float* out = (float*)d_out;
    _Float16* ws = (_Float16*)d_ws;   // 53,248 B used

    prep<<<dim3(4), 256, 0, stream>>>(W0, B0, W1, ws);

    dim3 grid(16, 1024);
    for (int layer = 0; layer < 4; ++layer) {
        const float* xin = (layer == 0) ? z : out;
        int writeA = (layer == 0) ? 1 : 0;
        int parityA = layer & 1;
        discrete_flow_layer<<<grid, 256, 0, stream>>>(
            xin, out,
            ws + layer * 5120,
            ws + 20480 + layer * 1536,
            B1 + layer * 16,
            W2 + layer * 144,
            B2 + layer * 1,
            parityA, writeA);
    }
}